// Round 3
// baseline (186.592 us; speedup 1.0000x reference)
//
#include <hip/hip_runtime.h>
#include <hip/hip_bf16.h>
#include <cstdint>

// DST-II as GEMM: Y[m][k] = sum_n X[m][n] * S[n][k],
// S[n][k] = sin(pi/N * (n+0.5) * (k+1)), N = 1024.
// R3: back to 128x128 tiles / 256 thr (4 blocks/CU co-resident for barrier
// overlap -- R2's 128x256 gave only 2/CU, occupancy-bound at 33%), keeping
// R2's XCD-aware swizzle that cut FETCH 265->42 MB.

#define M_TOT 16384
#define N_TOT 1024
#define K_TOT 1024

typedef __attribute__((ext_vector_type(8), may_alias)) __bf16 bf16x8;
typedef __attribute__((ext_vector_type(8), may_alias)) short s16x8;
typedef __attribute__((ext_vector_type(4))) float f32x4;

__device__ __forceinline__ unsigned short f2bf(float f) {
  unsigned int b = __float_as_uint(f);
  b += 0x7fffu + ((b >> 16) & 1u);   // RNE
  return (unsigned short)(b >> 16);
}

__device__ __forceinline__ void gl_lds16(const void* g, void* l) {
  __builtin_amdgcn_global_load_lds(
      (const __attribute__((address_space(1))) unsigned int*)(uintptr_t)g,
      (__attribute__((address_space(3))) unsigned int*)(uintptr_t)l,
      16, 0, 0);
}

// St[j][n] = sin(pi*(2n+1)*(j+1)/2048), bf16, row-major [1024][1024].
// Exact range reduction: (2n+1)(j+1) mod 4096 -> revolutions r/4096 in [0,1).
__global__ void gen_st(unsigned short* __restrict__ st) {
  const int idx = blockIdx.x * 256 + threadIdx.x;
  const int base = idx * 8;             // 8 consecutive n for one j
  const int j = base >> 10;
  const int n0 = base & 1023;
  const int jj = j + 1;
  unsigned int pk[4];
#pragma unroll
  for (int t = 0; t < 4; ++t) {
    int n = n0 + 2 * t;
    int r0 = ((2 * n + 1) * jj) & 4095;
    int r1 = ((2 * n + 3) * jj) & 4095;
    unsigned short lo = f2bf(__builtin_amdgcn_sinf((float)r0 * (1.0f / 4096.0f)));
    unsigned short hi = f2bf(__builtin_amdgcn_sinf((float)r1 * (1.0f / 4096.0f)));
    pk[t] = (unsigned int)lo | ((unsigned int)hi << 16);
  }
  *(uint4*)(st + base) = make_uint4(pk[0], pk[1], pk[2], pk[3]);
}

// C[m][j] = sum_n A[m][n] * Bt[j][n];  A fp32 [16384][1024], Bt bf16 [1024][1024]
// Block: 256 threads (4 waves, 2Mx2N), tile 128(M) x 128(N), BK=64, 16 K-iters.
// LDS tiles row-major, rows of 64 bf16 (128 B = 8 x 16B chunks), chunk XOR
// swizzle: data chunk c of row r stored at chunk position c ^ (r & 7).
__global__ __launch_bounds__(256, 4) void dst_gemm(
    const float* __restrict__ X, const unsigned short* __restrict__ St,
    float* __restrict__ Y) {
  __shared__ short As[128 * 64];   // 16 KB
  __shared__ short Bs[128 * 64];   // 16 KB

  const int t = threadIdx.x;
  const int l = t & 63;
  const int w = t >> 6;            // 0..3

  // XCD-aware swizzle (XCD = linear block id % 8), 1024 blocks.
  // XCD x runs bM-groups x*16..x*16+15; within an XCD, consecutive blocks
  // sweep all 8 bN for 4 bM-groups per 32-CU dispatch round:
  // A working set 4*512KB(fp32) + St 2MB ~ L2-resident.
  const int b = blockIdx.x;
  const int x = b & 7;
  const int s = b >> 3;            // 0..127
  const int bN = (s & 7) * 128;
  const int bM = (x * 16 + (s >> 3)) * 128;

  const int wm = (w >> 1) * 64;
  const int wn = (w & 1) * 64;
  const int quad = l >> 4;
  const int l15 = l & 15;

  f32x4 acc[4][4] = {};

  for (int k0 = 0; k0 < K_TOT; k0 += 64) {
    // ---- B tile: async global->LDS, 16 B/lane, 1024 chunks / 256 thr ----
#pragma unroll
    for (int i = 0; i < 4; ++i) {
      int p = i * 256 + t;
      int r = p >> 3;            // tile row 0..127
      int c_lds = p & 7;
      int c_g = c_lds ^ (r & 7); // source chunk that lives at this position
      const unsigned short* src = St + ((bN + r) * K_TOT + k0 + c_g * 8);
      gl_lds16(src, &Bs[p * 8]);
    }
    // ---- A tile: fp32 load -> bf16 -> swizzled ds_write_b128 ----
#pragma unroll
    for (int i = 0; i < 4; ++i) {
      int p = i * 256 + t;
      int r = p >> 3;            // 0..127
      int c = p & 7;
      const float* src = X + ((size_t)(bM + r) * K_TOT + k0 + c * 8);
      float4 v0 = *(const float4*)(src);
      float4 v1 = *(const float4*)(src + 4);
      s16x8 pk;
      pk[0] = (short)f2bf(v0.x); pk[1] = (short)f2bf(v0.y);
      pk[2] = (short)f2bf(v0.z); pk[3] = (short)f2bf(v0.w);
      pk[4] = (short)f2bf(v1.x); pk[5] = (short)f2bf(v1.y);
      pk[6] = (short)f2bf(v1.z); pk[7] = (short)f2bf(v1.w);
      *(s16x8*)&As[r * 64 + ((c ^ (r & 7)) * 8)] = pk;
    }
    __syncthreads();

    // ---- compute: 2 sub-steps of K=32, 16 MFMA each per wave ----
#pragma unroll
    for (int ss = 0; ss < 2; ++ss) {
      const int cc = ss * 4 + quad;   // data chunk holding k = ss*32+quad*8..+7
      bf16x8 af[4], bfr[4];
#pragma unroll
      for (int mi = 0; mi < 4; ++mi) {
        int mrow = wm + mi * 16 + l15;
        af[mi] = *(const bf16x8*)&As[mrow * 64 + ((cc ^ (mrow & 7)) * 8)];
      }
#pragma unroll
      for (int ni = 0; ni < 4; ++ni) {
        int nrow = wn + ni * 16 + l15;
        bfr[ni] = *(const bf16x8*)&Bs[nrow * 64 + ((cc ^ (nrow & 7)) * 8)];
      }
#pragma unroll
      for (int mi = 0; mi < 4; ++mi)
#pragma unroll
        for (int ni = 0; ni < 4; ++ni)
          acc[mi][ni] = __builtin_amdgcn_mfma_f32_16x16x32_bf16(
              af[mi], bfr[ni], acc[mi][ni], 0, 0, 0);
    }
    __syncthreads();
  }

  // ---- epilogue: C/D layout col = lane&15, row = quad*4 + reg ----
#pragma unroll
  for (int mi = 0; mi < 4; ++mi) {
#pragma unroll
    for (int ni = 0; ni < 4; ++ni) {
#pragma unroll
      for (int rr = 0; rr < 4; ++rr) {
        int gr = bM + wm + mi * 16 + quad * 4 + rr;
        int gc = bN + wn + ni * 16 + l15;
        Y[(size_t)gr * N_TOT + gc] = acc[mi][ni][rr];
      }
    }
  }
}

extern "C" void kernel_launch(void* const* d_in, const int* in_sizes, int n_in,
                              void* d_out, int out_size, void* d_ws, size_t ws_size,
                              hipStream_t stream) {
  const float* X = (const float*)d_in[0];
  float* Y = (float*)d_out;
  unsigned short* St = (unsigned short*)d_ws;   // 1024*1024 bf16 = 2 MiB

  gen_st<<<dim3(512), dim3(256), 0, stream>>>(St);

  dst_gemm<<<dim3(1024), dim3(256), 0, stream>>>(X, St, Y);
}

// Round 4
// 137.667 us; speedup vs baseline: 1.3554x; 1.3554x over previous
//
#include <hip/hip_runtime.h>
#include <cstdint>

// DST-II via FFT, one 1024-point transform per wave, no LDS, no barriers.
//
// Y_k = sum_n x_n sin(pi/N (n+1/2)(k+1))
//     = DCT-II(u)_{N-1-k},  u_n = (-1)^n x_n            [verified N=2]
// DCT-II via Makhoul: v_p = u_{2p} (p<512), v_{1023-p} = u_{2p+1}
//   => v_p = x_{2p} (p<512),  v_p = -x_{2047-2p} (p>=512)
// V = DFT_1024(v);  C_j = Re[e^{-i pi j/2048} V_j];  Y_k = C_{1023-k}.
//
// DFT_1024 four-step (n = l + 64 j, k = m + 16 h):
//   G[l][m]  = sum_j v[l+64j] W16^{jm}          (in-lane DIF-16, slots)
//   G'[l][m] = G[l][m] * e^{-2 pi i l m / 1024}  (per-lane twiddle)
//   X[m+16h] = sum_l G'[l][m] W64^{lh}           (cross-lane DIF-64, shfl_xor)
// DIF leaves slot i = G[brev4(i)], lane L = freq h = brev6(L).

__device__ __forceinline__ float sinr(float r) {   // sin(2*pi*r), r in [0,1)
  return __builtin_amdgcn_sinf(r);
}
__device__ __forceinline__ float cosr(float r) {   // cos(2*pi*r), r in [0,1)
  float t = r + 0.25f;
  t -= (t >= 1.0f) ? 1.0f : 0.0f;
  return __builtin_amdgcn_sinf(t);
}

#define N_PT 1024
#define ROWS_PER_WAVE 2

__global__ __launch_bounds__(256) void dst_fft(const float* __restrict__ X,
                                               float* __restrict__ Y) {
  static constexpr int BR4[16] = {0, 8, 4, 12, 2, 10, 6, 14,
                                  1, 9, 5, 13, 3, 11, 7, 15};
  // W16^o = e^{-2 pi i o/16}
  static constexpr float W16C[8] = {1.0f, 0.9238795325f, 0.7071067812f,
                                    0.3826834324f, 0.0f, -0.3826834324f,
                                    -0.7071067812f, -0.9238795325f};
  static constexpr float W16S[8] = {-0.0f, -0.3826834324f, -0.7071067812f,
                                    -0.9238795325f, -1.0f, -0.9238795325f,
                                    -0.7071067812f, -0.3826834324f};

  const int t = threadIdx.x;
  const int l = t & 63;
  const int wid = blockIdx.x * 4 + (t >> 6);       // 0..8191
  const int h = __brev((unsigned)l) >> 26;          // brev6(lane)

  // ---- row-independent twiddles (registers, reused across rows) ----
  // cross-lane stage twiddles: W_{2H}^{l & (H-1)}, H = 32>>st
  float cS[6], sS[6];
#pragma unroll
  for (int st = 0; st < 6; ++st) {
    int H = 32 >> st;
    float r = (float)(l & (H - 1)) / (float)(2 * H);
    cS[st] = cosr(r);
    sS[st] = -sinr(r);
  }
  // per-lane four-step twiddle: e^{-2 pi i l m/1024}, m = brev4(slot)
  float gc[16], gs[16];
#pragma unroll
  for (int i = 0; i < 16; ++i) {
    float r = (float)(l * BR4[i]) * (1.0f / 1024.0f);
    gc[i] = cosr(r);
    gs[i] = -sinr(r);
  }
  // DCT post-twiddle: cos/sin(pi j/2048), j = brev4(slot) + 16h
  float dc[16], dsn[16];
#pragma unroll
  for (int i = 0; i < 16; ++i) {
    float r = (float)(BR4[i] + 16 * h) * (1.0f / 4096.0f);
    dc[i] = cosr(r);
    dsn[i] = sinr(r);
  }

  for (int it = 0; it < ROWS_PER_WAVE; ++it) {
    const int row = wid * ROWS_PER_WAVE + it;
    const float* xr = X + (size_t)row * N_PT;

    // ---- load + fold even/odd permutation and (-1)^n sign ----
    // lane l, slot j<8 loads x[2p], x[2p+1], p = l + 64j.
    //   re[j]    = v[p]      = x[2p]
    //   re[15-j] = v[l+64(15-j)] = -x[2*(63-l)+128j+1]  (partner lane's .y)
    float re[16], im[16], odd[8];
#pragma unroll
    for (int j = 0; j < 8; ++j) {
      float2 v = *(const float2*)(xr + 2 * l + 128 * j);
      re[j] = v.x;
      odd[j] = v.y;
    }
#pragma unroll
    for (int j = 0; j < 8; ++j)
      re[15 - j] = -__shfl_xor(odd[j], 63);
#pragma unroll
    for (int i = 0; i < 16; ++i) im[i] = 0.0f;

    // ---- in-lane DIF-16 over slots ----
#pragma unroll
    for (int H = 8; H >= 1; H >>= 1) {
#pragma unroll
      for (int b = 0; b < 16; b += 2 * H) {
#pragma unroll
        for (int o = 0; o < H; ++o) {
          int i0 = b + o, i1 = i0 + H;
          float ar = re[i0] - re[i1], ai = im[i0] - im[i1];
          re[i0] += re[i1];
          im[i0] += im[i1];
          int tw = o * (8 / H);
          re[i1] = ar * W16C[tw] - ai * W16S[tw];
          im[i1] = ar * W16S[tw] + ai * W16C[tw];
        }
      }
    }

    // ---- per-lane four-step twiddle ----
#pragma unroll
    for (int i = 0; i < 16; ++i) {
      float tr = re[i] * gc[i] - im[i] * gs[i];
      im[i] = re[i] * gs[i] + im[i] * gc[i];
      re[i] = tr;
    }

    // ---- cross-lane DIF-64 via shfl_xor ----
#pragma unroll
    for (int st = 0; st < 6; ++st) {
      const int H = 32 >> st;
      const bool up = (l & H) != 0;
      const float c = up ? cS[st] : 1.0f;
      const float s = up ? sS[st] : 0.0f;
      const float sg = up ? -1.0f : 1.0f;
#pragma unroll
      for (int i = 0; i < 16; ++i) {
        float tr = __shfl_xor(re[i], H);
        float ti = __shfl_xor(im[i], H);
        float ar = tr + sg * re[i];
        float ai = ti + sg * im[i];
        re[i] = ar * c - ai * s;
        im[i] = ar * s + ai * c;
      }
    }

    // ---- DCT post-twiddle: C_j = Re*cos + Im*sin ----
    float cb[16];
#pragma unroll
    for (int i = 0; i < 16; ++i)
      cb[i] = re[i] * dc[i] + im[i] * dsn[i];

    // ---- store: Y[1023-j], j = brev4(i) + 16h.  Lane owns contiguous
    // elements [1008-16h .. 1023-16h]; element offset q holds m = 15-q,
    // which lives in slot brev4(15-q). ----
    float* yb = Y + (size_t)row * N_PT + (1008 - 16 * h);
#pragma unroll
    for (int g = 0; g < 4; ++g) {
      float4 o4;
      o4.x = cb[BR4[15 - (4 * g + 0)]];
      o4.y = cb[BR4[15 - (4 * g + 1)]];
      o4.z = cb[BR4[15 - (4 * g + 2)]];
      o4.w = cb[BR4[15 - (4 * g + 3)]];
      *(float4*)(yb + 4 * g) = o4;
    }
  }
}

extern "C" void kernel_launch(void* const* d_in, const int* in_sizes, int n_in,
                              void* d_out, int out_size, void* d_ws, size_t ws_size,
                              hipStream_t stream) {
  const float* X = (const float*)d_in[0];
  float* Y = (float*)d_out;
  // 16384 rows / (2 rows per wave) / (4 waves per block) = 2048 blocks
  dst_fft<<<dim3(2048), dim3(256), 0, stream>>>(X, Y);
}

// Round 5
// 118.917 us; speedup vs baseline: 1.5691x; 1.1577x over previous
//
#include <hip/hip_runtime.h>
#include <cstdint>

// DST-II via FFT, one 1024-point transform per wave.
// Y_k = DCT-II(u)_{N-1-k}, u_n = (-1)^n x_n; Makhoul: v_p = x_{2p} (p<512),
// v_p = -x_{2047-2p} (p>=512); V = DFT_1024(v); C_j = Re[e^{-i pi j/2048} V_j];
// Y_k = C_{1023-k}.
//
// DFT_1024, n = l + 64*n2 (l = lane, n2 = slot):
//  phase 1: in-lane DIF-16 over n2 -> slot s holds m2 = brev4(s);
//           twiddle W1024^{l*m2}.                       [validated in R4]
//  DFT_64 over l, l = c + 4d (c = l&3):
//   W64^{(c+4d)(m+16e)} = W64^{cm} * W4^{ce} * W16^{dm}
//   -> wave-level LDS transpose (lane' = c + 4*m2 holds all d)
//   -> in-lane DIT-16 over d (bit-rev input via read order, natural m out)
//   -> twiddle W64^{c*m}
//   -> cross-lane DFT_4 over c: 2 radix-2 DIF stages, shfl_xor(2), shfl_xor(1)
//      (quad-perm DPP class), output e = brev2(c).
//  k = m2 + 16*m + 256*e; then DCT post-twiddle, store Y[1023-k].

__device__ __forceinline__ float sinr(float r) {   // sin(2*pi*r)
  return __builtin_amdgcn_sinf(r);
}
__device__ __forceinline__ float cosr(float r) {   // cos(2*pi*r), r in [0,1)
  float t = r + 0.25f;
  t -= (t >= 1.0f) ? 1.0f : 0.0f;
  return __builtin_amdgcn_sinf(t);
}

__global__ __launch_bounds__(256) void dst_fft(const float* __restrict__ X,
                                               float* __restrict__ Y) {
  static constexpr int BR4[16] = {0, 8, 4, 12, 2, 10, 6, 14,
                                  1, 9, 5, 13, 3, 11, 7, 15};
  // W16^o = e^{-2 pi i o/16}
  static constexpr float W16C[8] = {1.0f, 0.9238795325f, 0.7071067812f,
                                    0.3826834324f, 0.0f, -0.3826834324f,
                                    -0.7071067812f, -0.9238795325f};
  static constexpr float W16S[8] = {-0.0f, -0.3826834324f, -0.7071067812f,
                                    -0.9238795325f, -1.0f, -0.9238795325f,
                                    -0.7071067812f, -0.3826834324f};

  // per-wave transpose buffer: 64 rows x 16 complex = 8 KB (row = 32 floats)
  __shared__ __align__(16) float lds_all[4][64 * 32];

  const int t = threadIdx.x;
  const int l = t & 63;
  const int w = t >> 6;
  float* lds = &lds_all[w][0];
  const int wid = blockIdx.x * 4 + w;          // 0..8191

  const int c = l & 3;
  const int m2l = l >> 2;                       // this lane's m2 after transpose
  const int e = ((c & 1) << 1) | (c >> 1);      // brev2(c)
  const int sstar = BR4[m2l];                   // column holding freq m2l
  const int chb = sstar >> 1;                   // its 16B chunk
  const int subo = (sstar & 1) * 2;             // float offset inside chunk

  // cached twiddle: e^{-2 pi i l m2/1024}, m2 = brev4(slot)
  float gc[16], gs[16];
#pragma unroll
  for (int i = 0; i < 16; ++i) {
    float r = (float)(l * BR4[i]) * (1.0f / 1024.0f);
    gc[i] = cosr(r);
    gs[i] = -sinr(r);
  }

#pragma unroll
  for (int it = 0; it < 2; ++it) {
    const int row = wid * 2 + it;
    const float* xr = X + (size_t)row * 1024;

    // ---- load + even/odd fold (validated layout) ----
    float re[16], im[16], odd[8];
#pragma unroll
    for (int j = 0; j < 8; ++j) {
      float2 v = *(const float2*)(xr + 2 * l + 128 * j);
      re[j] = v.x;
      odd[j] = v.y;
    }
#pragma unroll
    for (int j = 0; j < 8; ++j)
      re[15 - j] = -__shfl_xor(odd[j], 63);
#pragma unroll
    for (int i = 0; i < 16; ++i) im[i] = 0.0f;

    // ---- phase 1: in-lane DIF-16 over slots ----
#pragma unroll
    for (int H = 8; H >= 1; H >>= 1) {
#pragma unroll
      for (int b = 0; b < 16; b += 2 * H) {
#pragma unroll
        for (int o = 0; o < H; ++o) {
          int i0 = b + o, i1 = i0 + H;
          float ar = re[i0] - re[i1], ai = im[i0] - im[i1];
          re[i0] += re[i1];
          im[i0] += im[i1];
          int tw = o * (8 / H);
          re[i1] = ar * W16C[tw] - ai * W16S[tw];
          im[i1] = ar * W16S[tw] + ai * W16C[tw];
        }
      }
    }
    // twiddle W1024^{l*m2}
#pragma unroll
    for (int i = 0; i < 16; ++i) {
      float tr = re[i] * gc[i] - im[i] * gs[i];
      im[i] = re[i] * gs[i] + im[i] * gc[i];
      re[i] = tr;
    }

    // ---- wave-level LDS transpose (no barrier; DS is in-order per wave) ----
    __asm__ volatile("s_waitcnt lgkmcnt(0)" ::: "memory");
#pragma unroll
    for (int ch = 0; ch < 8; ++ch) {
      float4 v = make_float4(re[2 * ch], im[2 * ch],
                             re[2 * ch + 1], im[2 * ch + 1]);
      *(float4*)(lds + l * 32 + ((ch ^ (l & 7)) * 4)) = v;   // chunk-XOR swizzle
    }
    __asm__ volatile("s_waitcnt lgkmcnt(0)" ::: "memory");
    // read: row r = c + 4*brev4(i)  (bit-reversed d -> DIT natural output)
#pragma unroll
    for (int i = 0; i < 16; ++i) {
      int r = c + 4 * BR4[i];
      int cp = chb ^ (r & 7);
      float2 v = *(const float2*)(lds + r * 32 + cp * 4 + subo);
      re[i] = v.x;
      im[i] = v.y;
    }

    // ---- in-lane DIT-16 over d -> natural m ----
#pragma unroll
    for (int H = 1; H <= 8; H <<= 1) {
#pragma unroll
      for (int b = 0; b < 16; b += 2 * H) {
#pragma unroll
        for (int o = 0; o < H; ++o) {
          int i0 = b + o, i1 = i0 + H;
          int tw = o * (8 / H);
          float tr = re[i1] * W16C[tw] - im[i1] * W16S[tw];
          float ti = re[i1] * W16S[tw] + im[i1] * W16C[tw];
          re[i1] = re[i0] - tr;
          im[i1] = im[i0] - ti;
          re[i0] += tr;
          im[i0] += ti;
        }
      }
    }

    // ---- twiddle W64^{c*m} (inline sin/cos; c*m/64 < 1) ----
#pragma unroll
    for (int m = 0; m < 16; ++m) {
      float r = (float)(c * m) * (1.0f / 64.0f);
      float tc = cosr(r), ts = -sinr(r);
      float tr = re[m] * tc - im[m] * ts;
      im[m] = re[m] * ts + im[m] * tc;
      re[m] = tr;
    }

    // ---- cross-lane DFT_4 over c: DIF radix-2 x2 (quad-perm shuffles) ----
    {
      const float sgA = (c & 2) ? -1.0f : 1.0f;
      const bool rot = (c == 3);                 // *(-i) on high half, tw idx 1
      const float sgB = (c & 1) ? -1.0f : 1.0f;
#pragma unroll
      for (int i = 0; i < 16; ++i) {
        float tr = __shfl_xor(re[i], 2), ti = __shfl_xor(im[i], 2);
        float ar = tr + sgA * re[i], ai = ti + sgA * im[i];
        float br = rot ? ai : ar;
        float bi = rot ? -ar : ai;
        tr = __shfl_xor(br, 1);
        ti = __shfl_xor(bi, 1);
        re[i] = tr + sgB * br;
        im[i] = ti + sgB * bi;
      }
    }

    // ---- DCT post-twiddle + store: j = m2 + 16*m + 256*e, Y[1023-j] ----
    float* yr = Y + (size_t)row * 1024 + (1023 - m2l - 256 * e);
#pragma unroll
    for (int s2 = 0; s2 < 16; ++s2) {
      int j = m2l + 16 * s2 + 256 * e;
      float r = (float)j * (1.0f / 4096.0f);    // < 0.25
      yr[-16 * s2] = re[s2] * cosr(r) + im[s2] * sinr(r);
    }
  }
}

extern "C" void kernel_launch(void* const* d_in, const int* in_sizes, int n_in,
                              void* d_out, int out_size, void* d_ws, size_t ws_size,
                              hipStream_t stream) {
  const float* X = (const float*)d_in[0];
  float* Y = (float*)d_out;
  // 16384 rows / 2 rows per wave / 4 waves per block = 2048 blocks
  dst_fft<<<dim3(2048), dim3(256), 0, stream>>>(X, Y);
}